// Round 1
// 170.325 us; speedup vs baseline: 1.0143x; 1.0143x over previous
//
#include <hip/hip_runtime.h>
#include <math.h>

// TrafficAugmentation R9. One block per row (S=4096), 512 threads, PER=8, BLOCKED.
// vs R8 (cyclic windows, s_nxt round-trip through LDS):
//  - Window ownership cyclic -> blocked: thread tid owns positions [8t, 8t+8).
//    Own 15 delays live in registers (4x ds_read_b128); pass-1 does ZERO
//    per-window LDS reads (was 32 ds_read2_b32/thread).
//  - s_nxt LDS array eliminated: window ends live in nx8[] registers feeding
//    phase 2a directly (-8208 B LDS, -8 ds_write_b16, -1 b128 read).
//  - Phase 2b ownership blocked: initial jumps from registers (-8 gathers);
//    per-round table writes packed into ONE uint4 (was 8 ds_write_b16).
//  - Blocked windows correlate drain lengths within a wave (shared 0.21s
//    killer delays) -> lower worst-lane divergence in pass 2.
//  - nf/rem computed once in phase 3, cached in registers for 4b/4d.
// Exactness unchanged: serial fp32 r-=d[j] chain order; burst sums serial
// increasing-j; rem = buf - nf*1448.0f exact (nf*1448 < 2^24).

#define S_LEN 4096
#define BLOCK 512
#define PER   8
#define MSSF  1448.0f

// LDS region A (16416 B), sequential overlays:
//   dly f32[4104] (ph0-1) -> jmpA u16[4097]@0 + jmpB u16[4097]@8208 (ph2)
//   -> diff i32[4096] -> out f32[4096] (ph4)
#define OFF_A    0
#define OFF_JB   8208
#define OFF_MENT 16416    // u16[512]: chain entry+1 per segment (0 = unmarked)
#define OFF_WS   17440    // i32[8]
#define SMEM_SZ  17472

__global__ __launch_bounds__(BLOCK, 6) void traffic_kernel(
    const float* __restrict__ gx,
    const float* __restrict__ gd,
    const float* __restrict__ gr,
    float* __restrict__ gout)
{
    __shared__ __align__(16) unsigned char smem[SMEM_SZ];
    float*          s_dly  = (float*)(smem + OFF_A);
    unsigned short* s_jA   = (unsigned short*)(smem + OFF_A);
    unsigned short* s_jB   = (unsigned short*)(smem + OFF_JB);
    int*            s_diff = (int*)(smem + OFF_A);
    float*          s_out  = (float*)(smem + OFF_A);
    unsigned short* s_ment = (unsigned short*)(smem + OFF_MENT);
    int*            s_ws   = (int*)(smem + OFF_WS);

    const int tid = threadIdx.x;
    const int sb  = tid << 3;
    const size_t rowoff = (size_t)blockIdx.x * S_LEN;
    const float* px = gx + rowoff;
    const float* pd = gd + rowoff;
    const float* pr = gr + rowoff;

    // ---- Phase 0: prefetch own x / rtts (blocked, coalesced float4);
    // stage delays to LDS; pad +1e30 (delays > 0 => r strictly decreasing;
    // windows past row end self-terminate).
    float xreg[PER];
    float rt[PER];
    {
        float4 xa = *(const float4*)(px + sb);
        float4 xb = *(const float4*)(px + sb + 4);
        xreg[0]=xa.x; xreg[1]=xa.y; xreg[2]=xa.z; xreg[3]=xa.w;
        xreg[4]=xb.x; xreg[5]=xb.y; xreg[6]=xb.z; xreg[7]=xb.w;
        float4 ra = *(const float4*)(pr + sb);
        float4 rb = *(const float4*)(pr + sb + 4);
        rt[0]=ra.x; rt[1]=ra.y; rt[2]=ra.z; rt[3]=ra.w;
        rt[4]=rb.x; rt[5]=rb.y; rt[6]=rb.z; rt[7]=rb.w;
    }
    {
        const float4* pd4 = (const float4*)pd;
        float4* s4 = (float4*)s_dly;
        for (int q = tid; q < S_LEN / 4; q += BLOCK) s4[q] = pd4[q];
        if (tid < 8) s_dly[S_LEN + tid] = 1.0e30f;
    }
    __syncthreads();

    // Own-window delays -> registers (windows i=0..7 need dl[0..14]).
    float dl[16];
    {
        const float4* dv = (const float4*)(s_dly + sb);   // 32B-aligned
        float4 a0 = dv[0], a1 = dv[1], a2 = dv[2], a3 = dv[3];
        dl[0]=a0.x;  dl[1]=a0.y;  dl[2]=a0.z;  dl[3]=a0.w;
        dl[4]=a1.x;  dl[5]=a1.y;  dl[6]=a1.z;  dl[7]=a1.w;
        dl[8]=a2.x;  dl[9]=a2.y;  dl[10]=a2.z; dl[11]=a2.w;
        dl[12]=a3.x; dl[13]=a3.y; dl[14]=a3.z; dl[15]=a3.w;
    }

    // ---- Phase 1 pass 1: all 8 first-windows from registers (ILP) ----
    unsigned surv = 0;
    float rsv[PER];
    int nx8[PER];
#pragma unroll
    for (int i = 0; i < PER; ++i) {
        float r1 = rt[i] - dl[i];        // exact reference subtract order
        float r2 = r1 - dl[i + 1];
        float r3 = r2 - dl[i + 2];
        float r4 = r3 - dl[i + 3];
        float r5 = r4 - dl[i + 4];
        float r6 = r5 - dl[i + 5];
        float r7 = r6 - dl[i + 6];
        float r8 = r7 - dl[i + 7];
        // r strictly decreasing: first k with r_k<=0  ==  #(r_k>0)+1
        int c = (r1 > 0.0f) + (r2 > 0.0f) + (r3 > 0.0f) + (r4 > 0.0f) +
                (r5 > 0.0f) + (r6 > 0.0f) + (r7 > 0.0f) + (r8 > 0.0f);
        rsv[i] = r8;
        int nx = sb + i + c + 1;
        if (nx > S_LEN) nx = S_LEN;
        nx8[i] = nx;                     // survivors overwritten in pass 2
        if (c == 8) surv |= 1u << i;
    }

    // ---- Phase 1 pass 2: survivors, per-lane flattened drain (LDS) ----
    while (surv) {
        int i = __ffs(surv) - 1;
        surv &= surv - 1;
        float rr = rsv[0];
#pragma unroll
        for (int ii = 1; ii < PER; ++ii) rr = (i == ii) ? rsv[ii] : rr;
        int j = sb + i + 8;
        int nx;
        while (true) {
            float e0 = s_dly[j],     e1 = s_dly[j + 1];
            float e2 = s_dly[j + 2], e3 = s_dly[j + 3];
            float e4 = s_dly[j + 4], e5 = s_dly[j + 5];
            float e6 = s_dly[j + 6], e7 = s_dly[j + 7];
            float q1 = rr - e0;
            float q2 = q1 - e1;
            float q3 = q2 - e2;
            float q4 = q3 - e3;
            float q5 = q4 - e4;
            float q6 = q5 - e5;
            float q7 = q6 - e6;
            float q8 = q7 - e7;
            int c2 = (q1 > 0.0f) + (q2 > 0.0f) + (q3 > 0.0f) + (q4 > 0.0f) +
                     (q5 > 0.0f) + (q6 > 0.0f) + (q7 > 0.0f) + (q8 > 0.0f);
            if (c2 < 8) { nx = j + c2 + 1; break; }   // +1e30 pad forces exit
            j += 8;
            rr = q8;
        }
        if (nx > S_LEN) nx = S_LEN;
#pragma unroll
        for (int ii = 0; ii < PER; ++ii) nx8[ii] = (ii == i) ? nx : nx8[ii];
    }
    __syncthreads();                     // dly dead; region A -> jmpA/jmpB

    // ---- Phase 2a: dead-start patch; register fold -> jmp; packed b128
    // write; build nibble automaton. All from registers (no s_nxt).
    int own[PER];
    unsigned long long rel = 0x8ull << 32;   // nibble 8 self-loops
    {
#pragma unroll
        for (int i = 0; i < PER; ++i)
            if (!(xreg[i] > 0.0f)) nx8[i] = S_LEN;     // dead start: chain stops
        int ee[PER];
#pragma unroll
        for (int i = PER - 1; i >= 0; --i) {
            int v = nx8[i];                 // v > sb+i
            int e = v;
#pragma unroll
            for (int j2 = i + 1; j2 < PER; ++j2)
                if (v == sb + j2) e = ee[j2];
            ee[i] = e;
        }
        uint4 pk;
        pk.x = (unsigned)ee[0] | ((unsigned)ee[1] << 16);
        pk.y = (unsigned)ee[2] | ((unsigned)ee[3] << 16);
        pk.z = (unsigned)ee[4] | ((unsigned)ee[5] << 16);
        pk.w = (unsigned)ee[6] | ((unsigned)ee[7] << 16);
        *(uint4*)&s_jA[sb] = pk;            // byte offset 16*tid: aligned
#pragma unroll
        for (int i = 0; i < PER; ++i) {
            int r = nx8[i] - sb; if (r > 8) r = 8;     // in [1,8]
            rel |= (unsigned long long)r << (i << 2);
        }
#pragma unroll
        for (int i = 0; i < PER; ++i) own[i] = ee[i];
    }
    if (tid == 0) { s_jA[4096] = (unsigned short)4096; s_jB[4096] = (unsigned short)4096; }
    s_ment[tid] = (tid == 0) ? (unsigned short)1 : (unsigned short)0;
    __syncthreads();

    // ---- Phase 2b: 9 doubling rounds over the seg-entry chain (<=512 nodes,
    // <=1 per segment). Blocked ownership: gathers random, write is one
    // packed uint4. Mark value unique per segment -> races benign.
    {
        unsigned short* ja = s_jA;
        unsigned short* jb = s_jB;
        for (int k = 0; k < 9; ++k) {
            int ent = (int)s_ment[tid];
            int q = -1;
            if (ent) {
                int e = (int)ja[ent - 1];
                if (e < S_LEN) q = e;
            }
            if (k < 8) {
                int nv[PER];
#pragma unroll
                for (int i = 0; i < PER; ++i) nv[i] = (int)ja[own[i]];
                if (q >= 0) s_ment[q >> 3] = (unsigned short)(q + 1);
                uint4 pk;
                pk.x = (unsigned)nv[0] | ((unsigned)nv[1] << 16);
                pk.y = (unsigned)nv[2] | ((unsigned)nv[3] << 16);
                pk.z = (unsigned)nv[4] | ((unsigned)nv[5] << 16);
                pk.w = (unsigned)nv[6] | ((unsigned)nv[7] << 16);
                *(uint4*)&jb[sb] = pk;
#pragma unroll
                for (int i = 0; i < PER; ++i) own[i] = nv[i];
            } else {
                if (q >= 0) s_ment[q >> 3] = (unsigned short)(q + 1);
            }
            __syncthreads();
            unsigned short* t = ja; ja = jb; jb = t;
        }
    }

    // ---- Phase 2c: expand entry mark via register nibble automaton ----
    unsigned lm = 0;
    {
        int ent = (int)s_ment[tid];
        if (ent) {
            int p = ent - 1 - sb;            // 0..7 (entry is in own segment)
#pragma unroll
            for (int s = 0; s < PER; ++s) {
                lm |= (p < 8) ? (1u << p) : 0u;
                p = (int)((rel >> (p << 2)) & 15ull);   // nibble 8 -> 8 forever
            }
        }
    }

    // ---- Phase 3: burst sums. Own-segment part from registers (predicated
    // +0.0f adds: exact for positive values, serial order kept); cross-
    // segment tail from global. nf/rem cached for 4b/4d.
    int   nf8[PER];
    float rem8[PER];
    unsigned use = 0;
    int tsum = 0;
#pragma unroll
    for (int i = 0; i < PER; ++i) {
        int nf = 0;
        float rem = 0.0f;
        if ((lm >> i) & 1u) {
            float xp = xreg[i];
            if (xp > 0.0f) {               // dead start: chain stops, no burst
                use |= 1u << i;
                int e = nx8[i];
                int upper = e - sb;        // > i
                float sum = xp;
#pragma unroll
                for (int jj = i + 1; jj < PER; ++jj)
                    sum += (jj < upper) ? xreg[jj] : 0.0f;
                for (int j = sb + PER; j < e; ++j) sum += px[j];
                nf = (int)ceilf(sum / MSSF) - 1; if (nf < 0) nf = 0;
                rem = sum - (float)nf * MSSF;          // exact
                tsum += nf + (rem > 0.0f ? 1 : 0);
            }
        }
        nf8[i] = nf;
        rem8[i] = rem;
    }

    // ---- zero diff region (region A free after 2b) + block scan (fused
    // barrier: zeros and s_ws both visible after the scan barrier) ----
    {
        int4* d4 = (int4*)s_diff;
        int4 z; z.x = z.y = z.z = z.w = 0;
        d4[tid] = z;
        d4[tid + 512] = z;
    }
    int texcl;
    {
        int lane = tid & 63, wv = tid >> 6;
        int v = tsum;
        for (int off = 1; off < 64; off <<= 1) {
            int u = __shfl_up(v, off, 64);
            if (lane >= off) v += u;
        }
        if (lane == 63) s_ws[wv] = v;
        __syncthreads();
        int woff = 0;
        for (int w = 0; w < wv; ++w) woff += s_ws[w];
        texcl = woff + v - tsum;
    }

    // ---- Phase 4b: difference-array scatter (+1 start, -1 end) ----
    {
        int o = texcl;
#pragma unroll
        for (int i = 0; i < PER; ++i) {
            if ((use >> i) & 1u) {
                int nf = nf8[i];
                if (nf > 0) {
                    if (o < S_LEN) atomicAdd(&s_diff[o], 1);
                    int e2 = o + nf;
                    if (e2 < S_LEN) atomicAdd(&s_diff[e2], -1);  // OOB drop
                }
                o += nf + (rem8[i] > 0.0f ? 1 : 0);
            }
        }
    }
    __syncthreads();

    // ---- Phase 4c: block inclusive scan of diff -> cover writeback ----
    {
        int4 a = *(int4*)&s_diff[sb];
        int4 b = *(int4*)&s_diff[sb + 4];
        int v0 = a.x,      v1 = v0 + a.y, v2 = v1 + a.z, v3 = v2 + a.w;
        int v4 = v3 + b.x, v5 = v4 + b.y, v6 = v5 + b.z, v7 = v6 + b.w;
        int T = v7;
        int lane = tid & 63, wv = tid >> 6;
        int sc = T;
        for (int off = 1; off < 64; off <<= 1) {
            int u = __shfl_up(sc, off, 64);
            if (lane >= off) sc += u;
        }
        if (lane == 63) s_ws[wv] = sc;
        __syncthreads();
        int basev = 0;
        for (int w = 0; w < wv; ++w) basev += s_ws[w];
        basev += sc - T;                   // exclusive prefix for slot sb
        float4 fa, fb;
        fa.x = (basev + v0 > 0) ? MSSF : 0.0f;
        fa.y = (basev + v1 > 0) ? MSSF : 0.0f;
        fa.z = (basev + v2 > 0) ? MSSF : 0.0f;
        fa.w = (basev + v3 > 0) ? MSSF : 0.0f;
        fb.x = (basev + v4 > 0) ? MSSF : 0.0f;
        fb.y = (basev + v5 > 0) ? MSSF : 0.0f;
        fb.z = (basev + v6 > 0) ? MSSF : 0.0f;
        fb.w = (basev + v7 > 0) ? MSSF : 0.0f;
        *(float4*)&s_out[sb]     = fa;     // in-place over own diff slots: safe
        *(float4*)&s_out[sb + 4] = fb;
    }
    __syncthreads();

    // ---- Phase 4d: remainder scatter (rem slot never MSS-covered) ----
    {
        int o = texcl;
#pragma unroll
        for (int i = 0; i < PER; ++i) {
            if ((use >> i) & 1u) {
                int nf = nf8[i];
                float rem = rem8[i];
                int rp = o + nf;
                if (rem > 0.0f && rp < S_LEN) s_out[rp] = rem;
                o += nf + (rem > 0.0f ? 1 : 0);
            }
        }
    }
    __syncthreads();

    // ---- Phase 4e: coalesced store ----
    {
        float4* po4 = (float4*)(gout + rowoff);
        const float4* so4 = (const float4*)s_out;
        po4[tid]       = so4[tid];
        po4[tid + 512] = so4[tid + 512];
    }
}

extern "C" void kernel_launch(void* const* d_in, const int* in_sizes, int n_in,
                              void* d_out, int out_size, void* d_ws, size_t ws_size,
                              hipStream_t stream) {
    const float* x      = (const float*)d_in[0];
    const float* delays = (const float*)d_in[1];
    const float* rtts   = (const float*)d_in[2];
    float* out = (float*)d_out;
    int rows = in_sizes[0] / S_LEN;   // B = 2048
    traffic_kernel<<<rows, BLOCK, 0, stream>>>(x, delays, rtts, out);
}

// Round 2
// 169.037 us; speedup vs baseline: 1.0221x; 1.0076x over previous
//
#include <hip/hip_runtime.h>
#include <math.h>

// TrafficAugmentation R10. One block per row (S=4096), 512 threads, PER=8, BLOCKED.
// vs R9:
//  - s_dly LDS staging ELIMINATED. Own 24-delay neighborhood loaded from
//    global (L1-hot, float4); removes 16-way-conflict ds_read_b128 dl loads,
//    the staging loop, and TWO barriers (first sync is now after phase 2a).
//  - Register windows deepened 8 -> 16 (pass 1b, predicated on 1a survivors):
//    divergent drain entry rate ~15% -> ~1.6% of windows.
//  - Drain reads global with per-element OOB -> 1e30 predication (exact same
//    pad semantics as the old LDS +1e30 pad).
//  - Phase-3 cross-segment tail: full float4-pair batches (exact serial add
//    order, no predication) + guarded scalar remainder.
//  - 2b gathers guarded by own[i] < S_LEN (converged lanes stop hitting LDS).
//  - Wave-offset loops in both scans -> broadcast int4 reads + branchless sums.
// Exactness unchanged: serial fp32 r-=d[j] chain order; burst sums serial
// increasing-j; rem = buf - nf*1448.0f exact (nf*1448 < 2^24).

#define S_LEN 4096
#define BLOCK 512
#define PER   8
#define MSSF  1448.0f

// LDS region A (16416 B), sequential overlays:
//   jmpA u16[4097]@0 + jmpB u16[4097]@8208 (ph2) -> diff i32[4096] -> out f32[4096]
#define OFF_A    0
#define OFF_JB   8208
#define OFF_MENT 16416    // u16[512]: chain entry+1 per segment (0 = unmarked)
#define OFF_WS   17440    // i32[8]
#define SMEM_SZ  17472

// compile-time-index access to the 24-float delay neighborhood
#define EXT(K) ((K) < 16 ? dla[(K)] : dlb[(K) - 16])

__global__ __launch_bounds__(BLOCK, 8) void traffic_kernel(
    const float* __restrict__ gx,
    const float* __restrict__ gd,
    const float* __restrict__ gr,
    float* __restrict__ gout)
{
    __shared__ __align__(16) unsigned char smem[SMEM_SZ];
    unsigned short* s_jA   = (unsigned short*)(smem + OFF_A);
    unsigned short* s_jB   = (unsigned short*)(smem + OFF_JB);
    int*            s_diff = (int*)(smem + OFF_A);
    float*          s_out  = (float*)(smem + OFF_A);
    unsigned short* s_ment = (unsigned short*)(smem + OFF_MENT);
    int*            s_ws   = (int*)(smem + OFF_WS);

    const int tid = threadIdx.x;
    const int sb  = tid << 3;
    const size_t rowoff = (size_t)blockIdx.x * S_LEN;
    const float* px = gx + rowoff;
    const float* pd = gd + rowoff;
    const float* pr = gr + rowoff;

    // ---- Phase 0: all inputs blocked, from global (coalesced float4).
    // Delay neighborhood dla[0..15] = pd[sb..sb+15], dlb[0..7] = pd[sb+16..23];
    // OOB positions -> +1e30 (delays > 0 => r strictly decreasing; windows
    // past row end self-terminate, nx clamps to S_LEN).
    float xreg[PER];
    float rt[PER];
    {
        float4 xa = *(const float4*)(px + sb);
        float4 xb = *(const float4*)(px + sb + 4);
        xreg[0]=xa.x; xreg[1]=xa.y; xreg[2]=xa.z; xreg[3]=xa.w;
        xreg[4]=xb.x; xreg[5]=xb.y; xreg[6]=xb.z; xreg[7]=xb.w;
        float4 ra = *(const float4*)(pr + sb);
        float4 rb = *(const float4*)(pr + sb + 4);
        rt[0]=ra.x; rt[1]=ra.y; rt[2]=ra.z; rt[3]=ra.w;
        rt[4]=rb.x; rt[5]=rb.y; rt[6]=rb.z; rt[7]=rb.w;
    }
    float dla[16], dlb[8];
    if (sb + 16 <= S_LEN) {
        const float4* dv = (const float4*)(pd + sb);
        float4 a0 = dv[0], a1 = dv[1], a2 = dv[2], a3 = dv[3];
        dla[0]=a0.x;  dla[1]=a0.y;  dla[2]=a0.z;  dla[3]=a0.w;
        dla[4]=a1.x;  dla[5]=a1.y;  dla[6]=a1.z;  dla[7]=a1.w;
        dla[8]=a2.x;  dla[9]=a2.y;  dla[10]=a2.z; dla[11]=a2.w;
        dla[12]=a3.x; dla[13]=a3.y; dla[14]=a3.z; dla[15]=a3.w;
    } else {
#pragma unroll
        for (int q = 0; q < 16; ++q)
            dla[q] = (sb + q < S_LEN) ? pd[sb + q] : 1.0e30f;
    }
    if (sb + 24 <= S_LEN) {
        const float4* dv = (const float4*)(pd + sb + 16);
        float4 b0 = dv[0], b1 = dv[1];
        dlb[0]=b0.x; dlb[1]=b0.y; dlb[2]=b0.z; dlb[3]=b0.w;
        dlb[4]=b1.x; dlb[5]=b1.y; dlb[6]=b1.z; dlb[7]=b1.w;
    } else {
#pragma unroll
        for (int q = 0; q < 8; ++q)
            dlb[q] = (sb + 16 + q < S_LEN) ? pd[sb + 16 + q] : 1.0e30f;
    }

    // ---- Phase 1a: all 8 first-windows, depth 8, from registers ----
    unsigned surv = 0;
    float rsv[PER];
    int nx8[PER];
#pragma unroll
    for (int i = 0; i < PER; ++i) {
        float r1 = rt[i] - dla[i];       // exact reference subtract order
        float r2 = r1 - dla[i + 1];
        float r3 = r2 - dla[i + 2];
        float r4 = r3 - dla[i + 3];
        float r5 = r4 - dla[i + 4];
        float r6 = r5 - dla[i + 5];
        float r7 = r6 - dla[i + 6];
        float r8 = r7 - dla[i + 7];
        // r strictly decreasing: first k with r_k<=0  ==  #(r_k>0)+1
        int c = (r1 > 0.0f) + (r2 > 0.0f) + (r3 > 0.0f) + (r4 > 0.0f) +
                (r5 > 0.0f) + (r6 > 0.0f) + (r7 > 0.0f) + (r8 > 0.0f);
        rsv[i] = r8;
        int nx = sb + i + c + 1;
        if (nx > S_LEN) nx = S_LEN;
        nx8[i] = nx;                     // survivors overwritten below
        if (c == 8) surv |= 1u << i;
    }

    // ---- Phase 1b: depth 9..16 for 1a survivors, still registers ----
    unsigned surv2 = 0;
    if (surv) {
#pragma unroll
        for (int i = 0; i < PER; ++i) {
            if ((surv >> i) & 1u) {
                float rr = rsv[i];
                float q1 = rr - EXT(i + 8);
                float q2 = q1 - EXT(i + 9);
                float q3 = q2 - EXT(i + 10);
                float q4 = q3 - EXT(i + 11);
                float q5 = q4 - EXT(i + 12);
                float q6 = q5 - EXT(i + 13);
                float q7 = q6 - EXT(i + 14);
                float q8 = q7 - EXT(i + 15);
                int c2 = (q1 > 0.0f) + (q2 > 0.0f) + (q3 > 0.0f) + (q4 > 0.0f) +
                         (q5 > 0.0f) + (q6 > 0.0f) + (q7 > 0.0f) + (q8 > 0.0f);
                rsv[i] = q8;
                if (c2 == 8) {
                    surv2 |= 1u << i;
                } else {
                    int nx = sb + i + 8 + c2 + 1;
                    if (nx > S_LEN) nx = S_LEN;
                    nx8[i] = nx;
                }
            }
        }
    }

    // ---- Phase 1c: rare drain (window alive past 16), global reads with
    // per-element OOB -> 1e30 (same pad semantics).
    while (surv2) {
        int i = __ffs(surv2) - 1;
        surv2 &= surv2 - 1;
        float rr = rsv[0];
#pragma unroll
        for (int ii = 1; ii < PER; ++ii) rr = (i == ii) ? rsv[ii] : rr;
        int j = sb + i + 16;
        int nx;
        while (true) {
            float e0 = 1.0e30f, e1 = 1.0e30f, e2 = 1.0e30f, e3 = 1.0e30f;
            float e4 = 1.0e30f, e5 = 1.0e30f, e6 = 1.0e30f, e7 = 1.0e30f;
            if (j     < S_LEN) e0 = pd[j];
            if (j + 1 < S_LEN) e1 = pd[j + 1];
            if (j + 2 < S_LEN) e2 = pd[j + 2];
            if (j + 3 < S_LEN) e3 = pd[j + 3];
            if (j + 4 < S_LEN) e4 = pd[j + 4];
            if (j + 5 < S_LEN) e5 = pd[j + 5];
            if (j + 6 < S_LEN) e6 = pd[j + 6];
            if (j + 7 < S_LEN) e7 = pd[j + 7];
            float q1 = rr - e0;
            float q2 = q1 - e1;
            float q3 = q2 - e2;
            float q4 = q3 - e3;
            float q5 = q4 - e4;
            float q6 = q5 - e5;
            float q7 = q6 - e6;
            float q8 = q7 - e7;
            int c2 = (q1 > 0.0f) + (q2 > 0.0f) + (q3 > 0.0f) + (q4 > 0.0f) +
                     (q5 > 0.0f) + (q6 > 0.0f) + (q7 > 0.0f) + (q8 > 0.0f);
            if (c2 < 8) { nx = j + c2 + 1; break; }   // 1e30 pad forces exit
            j += 8;
            rr = q8;
        }
        if (nx > S_LEN) nx = S_LEN;
#pragma unroll
        for (int ii = 0; ii < PER; ++ii) nx8[ii] = (ii == i) ? nx : nx8[ii];
    }

    // ---- Phase 2a: dead-start patch; register fold -> jmp; packed b128
    // write; build nibble automaton. All from registers.
    int own[PER];
    unsigned long long rel = 0x8ull << 32;   // nibble 8 self-loops
    {
#pragma unroll
        for (int i = 0; i < PER; ++i)
            if (!(xreg[i] > 0.0f)) nx8[i] = S_LEN;     // dead start: chain stops
        int ee[PER];
#pragma unroll
        for (int i = PER - 1; i >= 0; --i) {
            int v = nx8[i];                 // v > sb+i
            int e = v;
#pragma unroll
            for (int j2 = i + 1; j2 < PER; ++j2)
                if (v == sb + j2) e = ee[j2];
            ee[i] = e;
        }
        uint4 pk;
        pk.x = (unsigned)ee[0] | ((unsigned)ee[1] << 16);
        pk.y = (unsigned)ee[2] | ((unsigned)ee[3] << 16);
        pk.z = (unsigned)ee[4] | ((unsigned)ee[5] << 16);
        pk.w = (unsigned)ee[6] | ((unsigned)ee[7] << 16);
        *(uint4*)&s_jA[sb] = pk;            // byte offset 16*tid: aligned
#pragma unroll
        for (int i = 0; i < PER; ++i) {
            int r = nx8[i] - sb; if (r > 8) r = 8;     // in [1,8]
            rel |= (unsigned long long)r << (i << 2);
        }
#pragma unroll
        for (int i = 0; i < PER; ++i) own[i] = ee[i];
    }
    if (tid == 0) { s_jA[4096] = (unsigned short)4096; s_jB[4096] = (unsigned short)4096; }
    s_ment[tid] = (tid == 0) ? (unsigned short)1 : (unsigned short)0;
    __syncthreads();

    // ---- Phase 2b: 9 doubling rounds over the seg-entry chain (<=512 nodes,
    // <=1 per segment). Converged entries (own==S_LEN) skip the gather.
    // Mark value unique per segment -> races benign.
    {
        unsigned short* ja = s_jA;
        unsigned short* jb = s_jB;
        for (int k = 0; k < 9; ++k) {
            int ent = (int)s_ment[tid];
            int q = -1;
            if (ent) {
                int e = (int)ja[ent - 1];
                if (e < S_LEN) q = e;
            }
            if (k < 8) {
                int nv[PER];
#pragma unroll
                for (int i = 0; i < PER; ++i) {
                    int o = own[i];
                    nv[i] = (o >= S_LEN) ? S_LEN : (int)ja[o];
                }
                if (q >= 0) s_ment[q >> 3] = (unsigned short)(q + 1);
                uint4 pk;
                pk.x = (unsigned)nv[0] | ((unsigned)nv[1] << 16);
                pk.y = (unsigned)nv[2] | ((unsigned)nv[3] << 16);
                pk.z = (unsigned)nv[4] | ((unsigned)nv[5] << 16);
                pk.w = (unsigned)nv[6] | ((unsigned)nv[7] << 16);
                *(uint4*)&jb[sb] = pk;
#pragma unroll
                for (int i = 0; i < PER; ++i) own[i] = nv[i];
            } else {
                if (q >= 0) s_ment[q >> 3] = (unsigned short)(q + 1);
            }
            __syncthreads();
            unsigned short* t = ja; ja = jb; jb = t;
        }
    }

    // ---- Phase 2c: expand entry mark via register nibble automaton ----
    unsigned lm = 0;
    {
        int ent = (int)s_ment[tid];
        if (ent) {
            int p = ent - 1 - sb;            // 0..7 (entry is in own segment)
#pragma unroll
            for (int s = 0; s < PER; ++s) {
                lm |= (p < 8) ? (1u << p) : 0u;
                p = (int)((rel >> (p << 2)) & 15ull);   // nibble 8 -> 8 forever
            }
        }
    }

    // ---- Phase 3: burst sums. Own-segment part from registers (predicated
    // +0.0f adds: exact for positive values, serial order kept); cross-
    // segment tail from global in float4 batches (exact serial order).
    int   nf8[PER];
    float rem8[PER];
    unsigned use = 0;
    int tsum = 0;
#pragma unroll
    for (int i = 0; i < PER; ++i) {
        int nf = 0;
        float rem = 0.0f;
        if ((lm >> i) & 1u) {
            float xp = xreg[i];
            if (xp > 0.0f) {               // dead start: chain stops, no burst
                use |= 1u << i;
                int e = nx8[i];
                int upper = e - sb;        // > i
                float sum = xp;
#pragma unroll
                for (int jj = i + 1; jj < PER; ++jj)
                    sum += (jj < upper) ? xreg[jj] : 0.0f;
                int j = sb + PER;
                for (; j + 8 <= e; j += 8) {
                    float4 a = *(const float4*)(px + j);
                    float4 b = *(const float4*)(px + j + 4);
                    sum += a.x; sum += a.y; sum += a.z; sum += a.w;
                    sum += b.x; sum += b.y; sum += b.z; sum += b.w;
                }
                for (; j < e; ++j) sum += px[j];
                nf = (int)ceilf(sum / MSSF) - 1; if (nf < 0) nf = 0;
                rem = sum - (float)nf * MSSF;          // exact
                tsum += nf + (rem > 0.0f ? 1 : 0);
            }
        }
        nf8[i] = nf;
        rem8[i] = rem;
    }

    // ---- zero diff region (region A free after 2b) + block scan (fused
    // barrier: zeros and s_ws both visible after the scan barrier) ----
    {
        int4* d4 = (int4*)s_diff;
        int4 z; z.x = z.y = z.z = z.w = 0;
        d4[tid] = z;
        d4[tid + 512] = z;
    }
    int texcl;
    {
        int lane = tid & 63, wv = tid >> 6;
        int v = tsum;
        for (int off = 1; off < 64; off <<= 1) {
            int u = __shfl_up(v, off, 64);
            if (lane >= off) v += u;
        }
        if (lane == 63) s_ws[wv] = v;
        __syncthreads();
        int4 w0 = *(const int4*)s_ws;          // broadcast reads
        int4 w1 = *(const int4*)(s_ws + 4);
        int woff = 0;
        woff += (wv > 0) ? w0.x : 0;
        woff += (wv > 1) ? w0.y : 0;
        woff += (wv > 2) ? w0.z : 0;
        woff += (wv > 3) ? w0.w : 0;
        woff += (wv > 4) ? w1.x : 0;
        woff += (wv > 5) ? w1.y : 0;
        woff += (wv > 6) ? w1.z : 0;
        texcl = woff + v - tsum;
    }

    // ---- Phase 4b: difference-array scatter (+1 start, -1 end) ----
    {
        int o = texcl;
#pragma unroll
        for (int i = 0; i < PER; ++i) {
            if ((use >> i) & 1u) {
                int nf = nf8[i];
                if (nf > 0) {
                    if (o < S_LEN) atomicAdd(&s_diff[o], 1);
                    int e2 = o + nf;
                    if (e2 < S_LEN) atomicAdd(&s_diff[e2], -1);  // OOB drop
                }
                o += nf + (rem8[i] > 0.0f ? 1 : 0);
            }
        }
    }
    __syncthreads();

    // ---- Phase 4c: block inclusive scan of diff -> cover writeback ----
    {
        int4 a = *(int4*)&s_diff[sb];
        int4 b = *(int4*)&s_diff[sb + 4];
        int v0 = a.x,      v1 = v0 + a.y, v2 = v1 + a.z, v3 = v2 + a.w;
        int v4 = v3 + b.x, v5 = v4 + b.y, v6 = v5 + b.z, v7 = v6 + b.w;
        int T = v7;
        int lane = tid & 63, wv = tid >> 6;
        int sc = T;
        for (int off = 1; off < 64; off <<= 1) {
            int u = __shfl_up(sc, off, 64);
            if (lane >= off) sc += u;
        }
        if (lane == 63) s_ws[wv] = sc;
        __syncthreads();
        int4 w0 = *(const int4*)s_ws;          // broadcast reads
        int4 w1 = *(const int4*)(s_ws + 4);
        int basev = 0;
        basev += (wv > 0) ? w0.x : 0;
        basev += (wv > 1) ? w0.y : 0;
        basev += (wv > 2) ? w0.z : 0;
        basev += (wv > 3) ? w0.w : 0;
        basev += (wv > 4) ? w1.x : 0;
        basev += (wv > 5) ? w1.y : 0;
        basev += (wv > 6) ? w1.z : 0;
        basev += sc - T;                   // exclusive prefix for slot sb
        float4 fa, fb;
        fa.x = (basev + v0 > 0) ? MSSF : 0.0f;
        fa.y = (basev + v1 > 0) ? MSSF : 0.0f;
        fa.z = (basev + v2 > 0) ? MSSF : 0.0f;
        fa.w = (basev + v3 > 0) ? MSSF : 0.0f;
        fb.x = (basev + v4 > 0) ? MSSF : 0.0f;
        fb.y = (basev + v5 > 0) ? MSSF : 0.0f;
        fb.z = (basev + v6 > 0) ? MSSF : 0.0f;
        fb.w = (basev + v7 > 0) ? MSSF : 0.0f;
        *(float4*)&s_out[sb]     = fa;     // in-place over own diff slots: safe
        *(float4*)&s_out[sb + 4] = fb;
    }
    __syncthreads();

    // ---- Phase 4d: remainder scatter (rem slot never MSS-covered) ----
    {
        int o = texcl;
#pragma unroll
        for (int i = 0; i < PER; ++i) {
            if ((use >> i) & 1u) {
                int nf = nf8[i];
                float rem = rem8[i];
                int rp = o + nf;
                if (rem > 0.0f && rp < S_LEN) s_out[rp] = rem;
                o += nf + (rem > 0.0f ? 1 : 0);
            }
        }
    }
    __syncthreads();

    // ---- Phase 4e: coalesced store ----
    {
        float4* po4 = (float4*)(gout + rowoff);
        const float4* so4 = (const float4*)s_out;
        po4[tid]       = so4[tid];
        po4[tid + 512] = so4[tid + 512];
    }
}

extern "C" void kernel_launch(void* const* d_in, const int* in_sizes, int n_in,
                              void* d_out, int out_size, void* d_ws, size_t ws_size,
                              hipStream_t stream) {
    const float* x      = (const float*)d_in[0];
    const float* delays = (const float*)d_in[1];
    const float* rtts   = (const float*)d_in[2];
    float* out = (float*)d_out;
    int rows = in_sizes[0] / S_LEN;   // B = 2048
    traffic_kernel<<<rows, BLOCK, 0, stream>>>(x, delays, rtts, out);
}